// Round 7
// baseline (77.576 us; speedup 1.0000x reference)
//
#include <hip/hip_runtime.h>
#include <cstddef>

#define XSZ 512
#define YSZ 512
#define NB  4
#define NC  64
#define NP  20000
#define H3 48
#define W3 160
#define H4 24
#define W4 80
#define H5 12
#define W5 40
#define HW3 (H3*W3)
#define HW4 (H4*W4)
#define HW5 (H5*W5)
#define SLOT_CAP 64      // winners/row: mean ~19.5, max over 2048 rows ~37; 64 safe
                         // (overflow handled correctly by phase D)

#define FILL_BLOCKS 256                    // 256 blk * 256 thr * 4 int4 = 4 MiB winner fill
#define T3_TILES (NB * ((HW3 + 63) / 64))  // 480
#define T4_TILES (NB * ((HW4 + 63) / 64))  // 120
#define T5_TILES (NB * ((HW5 + 63) / 64))  // 32

typedef float f4 __attribute__((ext_vector_type(4)));

// ---------------------------------------------------------------------------
// Fused init: winner <- -1 (int4 fill)  +  LDS-tiled transpose [B,C,H,W] ->
// [B,H,W,C] for all three images. Original images are read ONCE -> nt loads
// (don't pollute L2/L3); transposed outputs are re-read by k_fused -> normal
// stores (want them cached).
// ---------------------------------------------------------------------------
__global__ void __launch_bounds__(256)
k_init(int4* __restrict__ winner4,
       const float* __restrict__ c3, const float* __restrict__ c4,
       const float* __restrict__ c5,
       float* __restrict__ c3t, float* __restrict__ c4t, float* __restrict__ c5t) {
    int blk = blockIdx.x;
    if (blk < FILL_BLOCKS) {
        int base = blk * 1024 + threadIdx.x;
        int4 m1 = make_int4(-1, -1, -1, -1);
        winner4[base      ] = m1;
        winner4[base + 256] = m1;
        winner4[base + 512] = m1;
        winner4[base + 768] = m1;
        return;
    }
    __shared__ float lds[NC * 65];
    int t = blk - FILL_BLOCKS;
    const float* in; float* outp; int HW, tpb;
    if (t < T3_TILES)                      { in = c3; outp = c3t; HW = HW3; tpb = 120; }
    else if ((t -= T3_TILES) < T4_TILES)   { in = c4; outp = c4t; HW = HW4; tpb = 30; }
    else { t -= T4_TILES;                    in = c5; outp = c5t; HW = HW5; tpb = 8; }
    int b  = t / tpb;
    int p0 = (t - b * tpb) * 64;
    int lane = threadIdx.x & 63, wave = threadIdx.x >> 6;
    const float* in_b  = in   + (size_t)b * NC * HW;
    float*       out_b = outp + (size_t)b * HW * NC;

    int p = p0 + lane;
    if (p < HW) {
        for (int ch = wave; ch < NC; ch += 4)          // coalesced 256B reads
            lds[ch * 65 + lane] = __builtin_nontemporal_load(&in_b[(size_t)ch * HW + p]);
    }
    __syncthreads();
    for (int pp = wave; pp < 64; pp += 4) {            // coalesced 256B writes
        int pq = p0 + pp;
        if (pq < HW) out_b[(size_t)pq * NC + lane] = lds[lane * 65 + pp];
    }
}

// ---------------------------------------------------------------------------
// Scatter: winner[b][cx][cy] = max point-index p with contains>0
// (numpy fancy-assignment last-write-wins == max p)
// ---------------------------------------------------------------------------
__global__ void __launch_bounds__(256)
k_scatter(const int* __restrict__ coors, const int* __restrict__ contains,
          int* __restrict__ winner) {
    int idx = blockIdx.x * blockDim.x + threadIdx.x;   // b*NP + p
    if (idx >= NB * NP) return;
    if (contains[idx] <= 0) return;
    int b  = idx / NP;
    int p  = idx - b * NP;
    int cx = coors[idx * 3 + 1];
    int cy = coors[idx * 3 + 2];
    if ((unsigned)cx >= XSZ || (unsigned)cy >= YSZ) return;   // mode='drop'
    atomicMax(&winner[((size_t)b * XSZ + cx) * YSZ + cy], p);
}

// ---------------------------------------------------------------------------
// Bilinear, exact f32 replay of the reference arithmetic. Transposed [H,W,C]
// layout: per-tap wave read = 64 consecutive floats = one 256B segment.
// ---------------------------------------------------------------------------
__device__ __forceinline__ float bilinT(const float* __restrict__ img, int H, int W,
                                        float px, float py, int c) {
    float gx = px * 2.0f - 1.0f;
    float gy = py * 2.0f - 1.0f;
    float x = (gx + 1.0f) * 0.5f * (float)(W - 1);
    float y = (gy + 1.0f) * 0.5f * (float)(H - 1);
    float x0f = floorf(x), y0f = floorf(y);
    float wx1 = x - x0f,   wy1 = y - y0f;
    float wx0 = 1.0f - wx1, wy0 = 1.0f - wy1;
    int x0 = (int)x0f, y0 = (int)y0f;
    float acc = 0.0f;
#pragma unroll
    for (int dy = 0; dy < 2; ++dy) {
#pragma unroll
        for (int dx = 0; dx < 2; ++dx) {
            int xi = x0 + dx, yi = y0 + dy;
            bool valid = (xi >= 0) && (xi <= W - 1) && (yi >= 0) && (yi <= H - 1);
            int xc = min(max(xi, 0), W - 1);
            int yc = min(max(yi, 0), H - 1);
            float w = (dx ? wx1 : wx0) * (dy ? wy1 : wy0);
            float v = img[(size_t)(yc * W + xc) * NC + c];
            acc = fmaf(v, valid ? w : 0.0f, acc);
        }
    }
    return acc;
}

// generic-stride variant for the no-transpose fallback
__device__ __forceinline__ float bilinG(const float* __restrict__ img, int H, int W,
                                        float px, float py, int c, int sChan) {
    float gx = px * 2.0f - 1.0f;
    float gy = py * 2.0f - 1.0f;
    float x = (gx + 1.0f) * 0.5f * (float)(W - 1);
    float y = (gy + 1.0f) * 0.5f * (float)(H - 1);
    float x0f = floorf(x), y0f = floorf(y);
    float wx1 = x - x0f,   wy1 = y - y0f;
    float wx0 = 1.0f - wx1, wy0 = 1.0f - wy1;
    int x0 = (int)x0f, y0 = (int)y0f;
    float acc = 0.0f;
#pragma unroll
    for (int dy = 0; dy < 2; ++dy) {
#pragma unroll
        for (int dx = 0; dx < 2; ++dx) {
            int xi = x0 + dx, yi = y0 + dy;
            bool valid = (xi >= 0) && (xi <= W - 1) && (yi >= 0) && (yi <= H - 1);
            int xc = min(max(xi, 0), W - 1);
            int yc = min(max(yi, 0), H - 1);
            float w = (dx ? wx1 : wx0) * (dy ? wy1 : wy0);
            float v = img[(size_t)(yc * W + xc) + (size_t)c * sChan];
            acc = fmaf(v, valid ? w : 0.0f, acc);
        }
    }
    return acc;
}

// ---------------------------------------------------------------------------
// Fused sample + dense writer. One block per (b,x) output slab (64c x 512y,
// 128 KB). Phase A: scan winner row, build slot list (LDS). Phase B: one wave
// per winning cell computes the 3 bilinears (lane=channel, coalesced 256B
// taps) into vec[slot][65]. Phase C: exactly-once float4 dense write via
// NON-TEMPORAL stores (out is never re-read; keeps images L2/L3-resident).
// Phase D: overflow cells (>SLOT_CAP winners/row; ~never) scattered nt store.
// LDS ~19.3 KB -> 8 blocks/CU.
// ---------------------------------------------------------------------------
__global__ void __launch_bounds__(256)
k_fused(const float* __restrict__ pnts, const int* __restrict__ winner,
        const float* __restrict__ i3t, const float* __restrict__ i4t,
        const float* __restrict__ i5t, const float* __restrict__ dyn,
        float* __restrict__ out) {
    __shared__ float vec[SLOT_CAP * 65];     // 16.6 KB
    __shared__ unsigned short smap[YSZ];     // 1 KB, 0xFFFF = empty
    __shared__ unsigned short slist[YSZ];    // point index (<20000 fits u16)
    __shared__ unsigned short ylist[YSZ];
    __shared__ int cnt;

    int bx = blockIdx.x;                 // b*512 + x
    int b = bx >> 9, x = bx & 511;
    int tid = threadIdx.x;
    if (tid == 0) cnt = 0;
    __syncthreads();

    // --- phase A: row scan, slot assignment ---
    const int2* wrow2 = (const int2*)(winner + ((size_t)b * XSZ + x) * YSZ);
    int2 r2 = wrow2[tid];                // 2 consecutive y cells per thread
    {
        int y0 = tid * 2;
        int pv0 = r2.x, pv1 = r2.y;
        int s0 = 0xFFFF, s1 = 0xFFFF;
        if (pv0 >= 0) { s0 = atomicAdd(&cnt, 1); slist[s0] = (unsigned short)pv0;
                        ylist[s0] = (unsigned short)y0; }
        if (pv1 >= 0) { s1 = atomicAdd(&cnt, 1); slist[s1] = (unsigned short)pv1;
                        ylist[s1] = (unsigned short)(y0 + 1); }
        smap[y0]     = (unsigned short)s0;
        smap[y0 + 1] = (unsigned short)s1;
    }
    __syncthreads();
    int n = cnt;
    int nB = min(n, SLOT_CAP);

    // --- phase B: compute winning-cell channel vectors into LDS ---
    int wave = tid >> 6, lane = tid & 63;
    const float* i3b = i3t + (size_t)b * HW3 * NC;
    const float* i4b = i4t + (size_t)b * HW4 * NC;
    const float* i5b = i5t + (size_t)b * HW5 * NC;
    for (int s = wave; s < nB; s += 4) {
        int p = slist[s], y = ylist[s];
        int idx = b * NP + p;
        float px = pnts[idx * 2], py = pnts[idx * 2 + 1];
        float fa = bilinT(i3b, H3, W3, px, py, lane);
        float fb = bilinT(i4b, H4, W4, px, py, lane);
        float fc = bilinT(i5b, H5, W5, px, py, lane);
        size_t dbase = (((size_t)b * 3) * XSZ + x) * YSZ + y;
        float d0 = dyn[dbase];
        float d1 = dyn[dbase + (size_t)XSZ * YSZ];
        float d2 = dyn[dbase + (size_t)2 * XSZ * YSZ];
        vec[s * 65 + lane] = fa * d0 + fb * d1 + fc * d2;
    }
    __syncthreads();

    // --- phase C: exactly-once coalesced dense write (non-temporal) ---
    int lane_c = tid >> 7;               // 0 or 1
    int t7 = tid & 127;
    int y4 = t7 << 2;
    int s0 = smap[y4], s1 = smap[y4 + 1], s2 = smap[y4 + 2], s3 = smap[y4 + 3];
    bool h0 = s0 < SLOT_CAP, h1 = s1 < SLOT_CAP;
    bool h2 = s2 < SLOT_CAP, h3 = s3 < SLOT_CAP;
    size_t obase = (size_t)b * NC * XSZ * YSZ + (size_t)x * YSZ + y4;
    for (int cb = 0; cb < NC; cb += 2) {
        int c = cb + lane_c;
        f4 v = (f4)(0.0f);
        if (h0) v.x = vec[s0 * 65 + c];
        if (h1) v.y = vec[s1 * 65 + c];
        if (h2) v.z = vec[s2 * 65 + c];
        if (h3) v.w = vec[s3 * 65 + c];
        __builtin_nontemporal_store(v, (f4*)(out + obase + (size_t)c * (XSZ * YSZ)));
    }

    // --- phase D: overflow slots (practically never taken) ---
    if (n > SLOT_CAP) {
        __syncthreads();                 // order after phase-C zeros
        for (int s = SLOT_CAP + wave; s < n; s += 4) {
            int p = slist[s], y = ylist[s];
            int idx = b * NP + p;
            float px = pnts[idx * 2], py = pnts[idx * 2 + 1];
            float fa = bilinT(i3b, H3, W3, px, py, lane);
            float fb = bilinT(i4b, H4, W4, px, py, lane);
            float fc = bilinT(i5b, H5, W5, px, py, lane);
            size_t dbase = (((size_t)b * 3) * XSZ + x) * YSZ + y;
            float d0 = dyn[dbase];
            float d1 = dyn[dbase + (size_t)XSZ * YSZ];
            float d2 = dyn[dbase + (size_t)2 * XSZ * YSZ];
            __builtin_nontemporal_store(fa * d0 + fb * d1 + fc * d2,
                &out[(((size_t)b * NC + lane) * XSZ + x) * YSZ + y]);
        }
    }
}

// fallback: scattered direct store into pre-zeroed out, untransposed images
__global__ void __launch_bounds__(256)
k_samp_fb(const int* __restrict__ coors, const int* __restrict__ contains,
          const float* __restrict__ pnts, const int* __restrict__ winner,
          const float* __restrict__ i3, const float* __restrict__ i4,
          const float* __restrict__ i5, const float* __restrict__ dyn,
          float* __restrict__ out) {
    int nw   = gridDim.x << 2;
    int wv   = (blockIdx.x << 2) + (threadIdx.x >> 6);
    int lane = threadIdx.x & 63;
    for (int idx = wv; idx < NB * NP; idx += nw) {
        if (contains[idx] <= 0) continue;
        int b = idx / NP;
        int p = idx - b * NP;
        int cx = coors[idx * 3 + 1];
        int cy = coors[idx * 3 + 2];
        if ((unsigned)cx >= XSZ || (unsigned)cy >= YSZ) continue;
        if (winner[((size_t)b * XSZ + cx) * YSZ + cy] != p) continue;
        float px = pnts[idx * 2], py = pnts[idx * 2 + 1];
        float fa = bilinG(i3 + (size_t)b * NC * HW3, H3, W3, px, py, lane, HW3);
        float fb = bilinG(i4 + (size_t)b * NC * HW4, H4, W4, px, py, lane, HW4);
        float fc = bilinG(i5 + (size_t)b * NC * HW5, H5, W5, px, py, lane, HW5);
        size_t dbase = (((size_t)b * 3) * XSZ + cx) * YSZ + cy;
        float d0 = dyn[dbase];
        float d1 = dyn[dbase + (size_t)XSZ * YSZ];
        float d2 = dyn[dbase + (size_t)2 * XSZ * YSZ];
        out[(((size_t)b * NC + lane) * XSZ + cx) * YSZ + cy] = fa * d0 + fb * d1 + fc * d2;
    }
}

// fast zero-fill for fallback path
__global__ void k_zero4(float4* __restrict__ p, long n4) {
    long i = (long)blockIdx.x * blockDim.x + threadIdx.x;
    long stride = (long)gridDim.x * blockDim.x;
    for (; i < n4; i += stride) p[i] = make_float4(0.f, 0.f, 0.f, 0.f);
}

extern "C" void kernel_launch(void* const* d_in, const int* in_sizes, int n_in,
                              void* d_out, int out_size, void* d_ws, size_t ws_size,
                              hipStream_t stream) {
    const float* c3       = (const float*)d_in[0];
    const float* c4       = (const float*)d_in[1];
    const float* c5       = (const float*)d_in[2];
    const float* dyn      = (const float*)d_in[3];
    const float* pnts     = (const float*)d_in[4];
    const int*   coors    = (const int*)d_in[5];
    const int*   contains = (const int*)d_in[6];
    float* out = (float*)d_out;

    // workspace layout
    char* ws = (char*)d_ws;
    size_t off = 0;
    int* winner = (int*)(ws + off);   off += (size_t)NB * XSZ * YSZ * 4;   // 4 MiB
    float* c3t  = (float*)(ws + off); off += (size_t)NB * NC * HW3 * 4;    // 7.9 MB
    float* c4t  = (float*)(ws + off); off += (size_t)NB * NC * HW4 * 4;    // 2.0 MB
    float* c5t  = (float*)(ws + off); off += (size_t)NB * NC * HW5 * 4;    // 0.5 MB
    size_t t_need = off;                                                    // ~14.5 MB
    bool useT = (ws_size >= t_need);

    int npts = NB * NP;
    int init_blocks = useT ? (FILL_BLOCKS + T3_TILES + T4_TILES + T5_TILES)
                           : FILL_BLOCKS;
    k_init<<<init_blocks, 256, 0, stream>>>((int4*)winner, c3, c4, c5,
                                            c3t, c4t, c5t);
    k_scatter<<<(npts + 255) / 256, 256, 0, stream>>>(coors, contains, winner);

    if (useT) {
        // 3-dispatch main path: no output zero-fill, no intermediate buffer
        k_fused<<<NB * XSZ, 256, 0, stream>>>(pnts, winner, c3t, c4t, c5t,
                                              dyn, out);
    } else {
        long n4 = (long)out_size / 4;
        k_zero4<<<8192, 256, 0, stream>>>((float4*)out, n4);
        k_samp_fb<<<2048, 256, 0, stream>>>(coors, contains, pnts, winner,
                                            c3, c4, c5, dyn, out);
    }
}